// Round 9
// baseline (172.428 us; speedup 1.0000x reference)
//
#include <hip/hip_runtime.h>

#define N_ROWS 4096
#define D_K    2048
#define BMR 128          // tile rows (A panel)
#define BNC 256          // tile cols (B panel)
#define BK  32
#define NT  (D_K / BK)   // 64 K-tiles
#define MARGIN 0.3f

typedef unsigned short u16;
typedef __attribute__((ext_vector_type(8))) short bf16x8;
typedef __attribute__((ext_vector_type(4))) float f32x4;

__device__ __forceinline__ void stage16(const u16* src, u16* dst) {
    __builtin_amdgcn_global_load_lds((const __attribute__((address_space(1))) unsigned int*)src,
                                     (__attribute__((address_space(3))) unsigned int*)dst, 16, 0, 0);
}

__device__ __forceinline__ u16 f2bf(float f) {
    unsigned u = __float_as_uint(f);
    u += 0x7fffu + ((u >> 16) & 1u);   // round-to-nearest-even
    return (u16)(u >> 16);
}

// ---------- Kernel 1: fp32 -> bf16 convert, exact fp32 row norms, init ap2/an2 ----------
__global__ __launch_bounds__(256) void prep_kernel(
    const float* __restrict__ emb, u16* __restrict__ embB,
    float* __restrict__ xx, unsigned* __restrict__ ap2, unsigned* __restrict__ an2)
{
    const int row = blockIdx.x;
    const int t = threadIdx.x;
    const float4* src = (const float4*)(emb + (size_t)row * D_K);
    ushort4* dst = (ushort4*)(embB + (size_t)row * D_K);
    float s = 0.f;
#pragma unroll
    for (int i = 0; i < 2; ++i) {
        float4 v = src[t + i * 256];
        s = fmaf(v.x, v.x, s);
        s = fmaf(v.y, v.y, s);
        s = fmaf(v.z, v.z, s);
        s = fmaf(v.w, v.w, s);
        ushort4 o;
        o.x = f2bf(v.x); o.y = f2bf(v.y); o.z = f2bf(v.z); o.w = f2bf(v.w);
        dst[t + i * 256] = o;
    }
#pragma unroll
    for (int off = 32; off >= 1; off >>= 1) s += __shfl_down(s, off, 64);
    __shared__ float red[4];
    if ((t & 63) == 0) red[t >> 6] = s;
    __syncthreads();
    if (t == 0) {
        xx[row] = red[0] + red[1] + red[2] + red[3];
        ap2[row] = 0u;            // float 0.0
        an2[row] = 0x7f7fffffu;   // FLT_MAX
    }
}

// ---------- Kernel 2: flatmm-style — A direct from global (L1), B via LDS (3-buf) ----------
#define LDv(p)  (*(const bf16x8*)(p))
#define LDg(p)  (*(const bf16x8*)(p))
#define BARRIER()  __builtin_amdgcn_s_barrier()
#define VMW_(n)    asm volatile("s_waitcnt vmcnt(" #n ")" ::: "memory")
#define VMW(n)     VMW_(n)

// Stage one B K-tile (4 ops x 64 rows) into buffer B3_ (literal 0/1/2).
#define STAGEB(B3_, KTE_) do {                         \
    stage16(gB0 + (KTE_), lB + (B3_) * 8192);          \
    stage16(gB1 + (KTE_), lB + (B3_) * 8192 + 2048);   \
    stage16(gB2 + (KTE_), lB + (B3_) * 8192 + 4096);   \
    stage16(gB3 + (KTE_), lB + (B3_) * 8192 + 6144);   \
} while (0)

// One K-tile: B_ = LDS buf (LITERAL = T_%3). Stage B(t+2); A-frags direct global;
// one barrier; VMW(4) drains B(t+1), leaves B(t+2) in flight.
#define KT32(B_, T_)                                                                  \
  {                                                                                   \
    const bool ok = ((T_) + 2 < NT);                                                  \
    if (ok) { STAGEB(((B_) + 2) % 3, ((T_) + 2) * BK); }                              \
    bf16x8 aq[8], bq[4];                                                              \
    _Pragma("unroll")                                                                 \
    for (int n = 0; n < 4; ++n)                                                       \
        bq[n] = LDv(BB + (B_) * 16384 + bOff + n * 1024 + kx);                        \
    _Pragma("unroll")                                                                 \
    for (int m = 0; m < 8; ++m)                                                       \
        aq[m] = LDg(gAf + m * (16 * D_K) + (T_) * BK);                                \
    __builtin_amdgcn_s_setprio(1);                                                    \
    _Pragma("unroll")                                                                 \
    for (int m = 0; m < 8; ++m)                                                       \
        _Pragma("unroll")                                                             \
        for (int n = 0; n < 4; ++n)                                                   \
            acc[m][n] = __builtin_amdgcn_mfma_f32_16x16x32_bf16(aq[m], bq[n], acc[m][n], 0, 0, 0); \
    __builtin_amdgcn_s_setprio(0);                                                    \
    if (ok) { VMW(4); } else { VMW(0); }                                              \
    BARRIER();                                                                        \
  }

__global__ __launch_bounds__(256, 2) void gram_reduce_kernel(
    const u16* __restrict__ embB, const float* __restrict__ xx,
    const int* __restrict__ lab, unsigned* __restrict__ ap2, unsigned* __restrict__ an2)
{
    __shared__ u16 Bsh[3 * BNC * BK];   // 48 KiB: [buf][256 rows][32 cols], swizzled 16B slots
    __shared__ int labR[BMR], labC[BNC];
    __shared__ float xxR[BMR], xxC[BNC];

    const int tid = threadIdx.x;
    const int bid = blockIdx.x;
    const int swz = (bid & 7) * 64 + (bid >> 3);   // bijective: 512 % 8 == 0
    const int bm = swz >> 4, bn = swz & 15;        // 32 row-panels x 16 col-panels
    const int row0 = bm * BMR, col0 = bn * BNC;

    // ---- B staging: linear LDS dest (base + tid*16B), pre-swizzled global source.
    // Row = 64B = 4 slots of 16B; involution: slot ^= (row>>1)&3.
    const int csw = ((tid & 3) ^ ((tid >> 3) & 3)) * 8;   // u16 elements
    const int srow = tid >> 2;                            // 0..63
    const u16* gB0 = embB + (size_t)(col0 + srow) * D_K + csw;
    const u16* gB1 = embB + (size_t)(col0 + 64 + srow) * D_K + csw;
    const u16* gB2 = embB + (size_t)(col0 + 128 + srow) * D_K + csw;
    const u16* gB3 = embB + (size_t)(col0 + 192 + srow) * D_K + csw;
    u16* lB = Bsh + tid * 8;

    // ---- fragment constants (wave w of 4 owns cols w*64..w*64+63, all 128 rows)
    const int l = tid & 63, w = tid >> 6;
    const int fr = l & 15, fkb = l >> 4;            // frag row / k-slot (0..3)
    const int kx = (fkb ^ ((fr >> 1) & 3)) * 16;    // swizzled 16B slot within 64B row (bytes)
    const char* BB = (const char*)Bsh;
    const int bOff = w * 4096 + fr * 64;            // + buf*16384 + n*1024 (bytes)

    // ---- A direct-from-global per-lane base: row (row0+fr), k-slot fkb (elements)
    const u16* gAf = embB + (size_t)(row0 + fr) * D_K + fkb * 8;

    f32x4 acc[8][4];
#pragma unroll
    for (int m = 0; m < 8; ++m)
#pragma unroll
        for (int n = 0; n < 4; ++n) acc[m][n] = (f32x4){0.f, 0.f, 0.f, 0.f};

    // ---- prologue: B tiles 0,1 staged; drain tile 0 (4 newest = tile 1 stay in flight)
    STAGEB(0, 0);
    STAGEB(1, BK);
    VMW(4);
    BARRIER();

    // ---- main loop: 3 K-tiles per iteration (buf = tile%3 as literal); tail tile 63
    for (int ii = 0; ii < 21; ++ii) {
        const int t3 = 3 * ii;
        KT32(0, t3)
        KT32(1, t3 + 1)
        KT32(2, t3 + 2)
    }
    KT32(0, 63)

    // ---- epilogue metadata (only needed here)
    { int u2 = tid; labC[u2] = lab[col0 + u2]; xxC[u2] = xx[col0 + u2]; }
    if (tid < 128) { labR[tid] = lab[row0 + tid]; xxR[tid] = xx[row0 + tid]; }
    __syncthreads();

    // ---- epilogue: d2 = xx_i + xx_j - 2g, clamp, masked max/min, 16-lane reduce, atomics
    const int rgrp = l >> 4;
#pragma unroll
    for (int m = 0; m < 8; ++m) {
#pragma unroll
        for (int r = 0; r < 4; ++r) {
            const int il = m * 16 + rgrp * 4 + r;          // C/D row = (lane>>4)*4 + reg
            const int li = labR[il];
            const float xi = xxR[il];
            float apv = 0.f, anv = __FLT_MAX__;
#pragma unroll
            for (int n = 0; n < 4; ++n) {
                const int jl = w * 64 + n * 16 + fr;       // C/D col = lane&15
                float d2 = xi + xxC[jl] - 2.f * acc[m][n][r];
                d2 = fmaxf(d2, 1e-12f);
                const bool same = (labC[jl] == li);
                apv = same ? fmaxf(apv, d2) : apv;
                anv = same ? anv : fminf(anv, d2);
            }
#pragma unroll
            for (int off = 1; off < 16; off <<= 1) {
                apv = fmaxf(apv, __shfl_xor(apv, off, 64));
                anv = fminf(anv, __shfl_xor(anv, off, 64));
            }
            if (fr == 0) {
                atomicMax(&ap2[row0 + il], __float_as_uint(apv));
                atomicMin(&an2[row0 + il], __float_as_uint(anv));
            }
        }
    }
}

// ---------- Kernel 3: finalize loss + precision ----------
__global__ __launch_bounds__(256) void finalize_kernel(
    const unsigned* __restrict__ ap2, const unsigned* __restrict__ an2, float* __restrict__ out)
{
    const int t = threadIdx.x;
    float ls = 0.f, ps = 0.f;
    for (int i = t; i < N_ROWS; i += 256) {
        const float ap = sqrtf(__uint_as_float(ap2[i]));
        const float an = sqrtf(__uint_as_float(an2[i]));
        ls += fmaxf(MARGIN - an + ap, 0.f);
        ps += (an > ap) ? 1.f : 0.f;
    }
#pragma unroll
    for (int off = 32; off >= 1; off >>= 1) {
        ls += __shfl_down(ls, off, 64);
        ps += __shfl_down(ps, off, 64);
    }
    __shared__ float rl[4], rp[4];
    if ((t & 63) == 0) { rl[t >> 6] = ls; rp[t >> 6] = ps; }
    __syncthreads();
    if (t == 0) {
        out[0] = (rl[0] + rl[1] + rl[2] + rl[3]) * (1.f / N_ROWS);
        out[1] = (rp[0] + rp[1] + rp[2] + rp[3]) * (1.f / N_ROWS);
    }
}

extern "C" void kernel_launch(void* const* d_in, const int* in_sizes, int n_in,
                              void* d_out, int out_size, void* d_ws, size_t ws_size,
                              hipStream_t stream)
{
    const float* emb = (const float*)d_in[0];
    const int* lab = (const int*)d_in[1];
    float* out = (float*)d_out;

    char* ws = (char*)d_ws;
    u16* embB   = (u16*)ws;                                           // 16 MB
    float* xx   = (float*)(ws + (size_t)N_ROWS * D_K * 2);
    unsigned* ap2 = (unsigned*)(ws + (size_t)N_ROWS * D_K * 2 + N_ROWS * 4);
    unsigned* an2 = (unsigned*)(ws + (size_t)N_ROWS * D_K * 2 + 2 * (size_t)N_ROWS * 4);

    prep_kernel<<<N_ROWS, 256, 0, stream>>>(emb, embB, xx, ap2, an2);
    dim3 grid((N_ROWS / BMR) * (N_ROWS / BNC));   // 32*16 = 512 blocks, 2 per CU
    gram_reduce_kernel<<<grid, 256, 0, stream>>>(embB, xx, lab, ap2, an2);
    finalize_kernel<<<1, 256, 0, stream>>>(ap2, an2, out);
}

// Round 10
// 87.003 us; speedup vs baseline: 1.9819x; 1.9819x over previous
//
#include <hip/hip_runtime.h>

#define N_ROWS 4096
#define D_K    2048
#define BM 256
#define BK 64
#define NT (D_K / BK)   // 32 K-tiles
#define MARGIN 0.3f

typedef unsigned short u16;
typedef __attribute__((ext_vector_type(8))) short bf16x8;
typedef __attribute__((ext_vector_type(4))) float f32x4;

__device__ __forceinline__ void stage16(const u16* src, u16* dst) {
    __builtin_amdgcn_global_load_lds((const __attribute__((address_space(1))) unsigned int*)src,
                                     (__attribute__((address_space(3))) unsigned int*)dst, 16, 0, 0);
}

__device__ __forceinline__ u16 f2bf(float f) {
    unsigned u = __float_as_uint(f);
    u += 0x7fffu + ((u >> 16) & 1u);   // round-to-nearest-even
    return (u16)(u >> 16);
}

// ---------- Kernel 1: fp32 -> bf16 convert, exact fp32 row norms, init ap2/an2 ----------
__global__ __launch_bounds__(256) void prep_kernel(
    const float* __restrict__ emb, u16* __restrict__ embB,
    float* __restrict__ xx, unsigned* __restrict__ ap2, unsigned* __restrict__ an2)
{
    const int row = blockIdx.x;
    const int t = threadIdx.x;
    const float4* src = (const float4*)(emb + (size_t)row * D_K);
    ushort4* dst = (ushort4*)(embB + (size_t)row * D_K);
    float s = 0.f;
#pragma unroll
    for (int i = 0; i < 2; ++i) {
        float4 v = src[t + i * 256];
        s = fmaf(v.x, v.x, s);
        s = fmaf(v.y, v.y, s);
        s = fmaf(v.z, v.z, s);
        s = fmaf(v.w, v.w, s);
        ushort4 o;
        o.x = f2bf(v.x); o.y = f2bf(v.y); o.z = f2bf(v.z); o.w = f2bf(v.w);
        dst[t + i * 256] = o;
    }
#pragma unroll
    for (int off = 32; off >= 1; off >>= 1) s += __shfl_down(s, off, 64);
    __shared__ float red[4];
    if ((t & 63) == 0) red[t >> 6] = s;
    __syncthreads();
    if (t == 0) {
        xx[row] = red[0] + red[1] + red[2] + red[3];
        ap2[row] = 0u;            // float 0.0
        an2[row] = 0x7f7fffffu;   // FLT_MAX
    }
}

// ---------- Kernel 2: 256^2 4-phase MFMA gram + fused masked max/min reduction ----------
#define MM(mi, ni, ai, bi) \
    acc[mi][ni] = __builtin_amdgcn_mfma_f32_16x16x32_bf16(aq[ai][0], bq[bi][0], acc[mi][ni], 0, 0, 0); \
    acc[mi][ni] = __builtin_amdgcn_mfma_f32_16x16x32_bf16(aq[ai][1], bq[bi][1], acc[mi][ni], 0, 0, 0);

#define LDv(p) (*(const bf16x8*)(p))

// A chunk (h half, c sub-chunk of 64 rows), B chunk q (64 rows). b = buffer index (LITERAL 0/1).
#define STAGE_A(b, h, c, kt) stage16(gA + ((h) * 2 + (c)) * g64 + (kt), lA + ((b) * 16384 + ((h) * 128 + (c) * 64) * 64))
#define STAGE_B(b, q, kt)    stage16(gB + (q) * g64 + (kt),             lB + ((b) * 16384 + (q) * 4096))

#define BARRIER()  __builtin_amdgcn_s_barrier()
#define LGKM0()    asm volatile("s_waitcnt lgkmcnt(0)" ::: "memory")
#define VMW_(n)    asm volatile("s_waitcnt vmcnt(" #n ")" ::: "memory")
#define VMW(n)     VMW_(n)

// One K-tile. Stage targets tile t+1: {ph0: A-c0, ph1: B-q01, ph2: B-q23, ph3: A-c1}.
// Reads of tile t: {ph0: A m0-3 + B n0-1, ph1: B n2-3, ph2: A m4-7, ph3: NONE (regs held)}.
// Publish deadlines (lag-3): end-ph0 vmcnt(4) -> B-q23(t); end-ph1 vmcnt(4) -> A-c1(t);
// end-ph2 none; end-ph3 vmcnt(4) -> A-c0,B-q01(t+1). Tail (OKS_=0): 2/0/-/0.
#define KTILE(B_, NB_, KT1_, OKS_)                                                    \
  {                                                                                   \
    bf16x8 aq[4][2], bq[4][2];                                                        \
    /* ---- phase 0: read A m0-3 (8) + B n0-1 (4); stage A-c0(next) */                \
    aq[0][0] = LDv(AB + (B_)*32768 + aOff +    0 + kx0);                              \
    aq[0][1] = LDv(AB + (B_)*32768 + aOff +    0 + kx1);                              \
    aq[1][0] = LDv(AB + (B_)*32768 + aOff + 2048 + kx0);                              \
    aq[1][1] = LDv(AB + (B_)*32768 + aOff + 2048 + kx1);                              \
    aq[2][0] = LDv(AB + (B_)*32768 + aOff + 4096 + kx0);                              \
    aq[2][1] = LDv(AB + (B_)*32768 + aOff + 4096 + kx1);                              \
    aq[3][0] = LDv(AB + (B_)*32768 + aOff + 6144 + kx0);                              \
    aq[3][1] = LDv(AB + (B_)*32768 + aOff + 6144 + kx1);                              \
    bq[0][0] = LDv(BB + (B_)*32768 + bOff +    0 + kx0);                              \
    bq[0][1] = LDv(BB + (B_)*32768 + bOff +    0 + kx1);                              \
    bq[1][0] = LDv(BB + (B_)*32768 + bOff + 2048 + kx0);                              \
    bq[1][1] = LDv(BB + (B_)*32768 + bOff + 2048 + kx1);                              \
    if (OKS_) { STAGE_A(NB_, 0, 0, KT1_); STAGE_A(NB_, 1, 0, KT1_); }                 \
    asm volatile("s_waitcnt lgkmcnt(8)" ::: "memory");                                \
    BARRIER(); LGKM0();                                                               \
    __builtin_amdgcn_s_setprio(1);                                                    \
    MM(0, 0, 0, 0) MM(1, 1, 1, 1) MM(2, 0, 2, 0) MM(3, 1, 3, 1)                       \
    MM(0, 1, 0, 1) MM(1, 0, 1, 0) MM(2, 1, 2, 1) MM(3, 0, 3, 0)                       \
    __builtin_amdgcn_s_setprio(0);                                                    \
    if (OKS_) { VMW(4); } else { VMW(2); }                                            \
    BARRIER();                                                                        \
    /* ---- phase 1: read B n2-3 into bq[2-3] (4); stage B-q0,q1(next) */             \
    bq[2][0] = LDv(BB + (B_)*32768 + bOff + 4096 + kx0);                              \
    bq[2][1] = LDv(BB + (B_)*32768 + bOff + 4096 + kx1);                              \
    bq[3][0] = LDv(BB + (B_)*32768 + bOff + 6144 + kx0);                              \
    bq[3][1] = LDv(BB + (B_)*32768 + bOff + 6144 + kx1);                              \
    if (OKS_) { STAGE_B(NB_, 0, KT1_); STAGE_B(NB_, 1, KT1_); }                       \
    BARRIER(); LGKM0();                                                               \
    __builtin_amdgcn_s_setprio(1);                                                    \
    MM(0, 2, 0, 2) MM(1, 3, 1, 3) MM(2, 2, 2, 2) MM(3, 3, 3, 3)                       \
    MM(0, 3, 0, 3) MM(1, 2, 1, 2) MM(2, 3, 2, 3) MM(3, 2, 3, 2)                       \
    __builtin_amdgcn_s_setprio(0);                                                    \
    if (OKS_) { VMW(4); } else { VMW(0); }                                            \
    BARRIER();                                                                        \
    /* ---- phase 2: read A m4-7 into aq (8); stage B-q2,q3(next) */                  \
    aq[0][0] = LDv(AB + (B_)*32768 + aOff +  8192 + kx0);                             \
    aq[0][1] = LDv(AB + (B_)*32768 + aOff +  8192 + kx1);                             \
    aq[1][0] = LDv(AB + (B_)*32768 + aOff + 10240 + kx0);                             \
    aq[1][1] = LDv(AB + (B_)*32768 + aOff + 10240 + kx1);                             \
    aq[2][0] = LDv(AB + (B_)*32768 + aOff + 12288 + kx0);                             \
    aq[2][1] = LDv(AB + (B_)*32768 + aOff + 12288 + kx1);                             \
    aq[3][0] = LDv(AB + (B_)*32768 + aOff + 14336 + kx0);                             \
    aq[3][1] = LDv(AB + (B_)*32768 + aOff + 14336 + kx1);                             \
    if (OKS_) { STAGE_B(NB_, 2, KT1_); STAGE_B(NB_, 3, KT1_); }                       \
    BARRIER(); LGKM0();                                                               \
    __builtin_amdgcn_s_setprio(1);                                                    \
    MM(4, 2, 0, 2) MM(5, 3, 1, 3) MM(6, 2, 2, 2) MM(7, 3, 3, 3)                       \
    MM(4, 3, 0, 3) MM(5, 2, 1, 2) MM(6, 3, 2, 3) MM(7, 2, 3, 2)                       \
    __builtin_amdgcn_s_setprio(0);                                                    \
    BARRIER();                                                                        \
    /* ---- phase 3: NO reads (aq=A m4-7, bq01 held); stage A-c1(next); pure MFMA */  \
    if (OKS_) { STAGE_A(NB_, 0, 1, KT1_); STAGE_A(NB_, 1, 1, KT1_); }                 \
    BARRIER();                                                                        \
    __builtin_amdgcn_s_setprio(1);                                                    \
    MM(4, 0, 0, 0) MM(5, 1, 1, 1) MM(6, 0, 2, 0) MM(7, 1, 3, 1)                       \
    MM(4, 1, 0, 1) MM(5, 0, 1, 0) MM(6, 1, 2, 1) MM(7, 0, 3, 0)                       \
    __builtin_amdgcn_s_setprio(0);                                                    \
    if (OKS_) { VMW(4); } else { VMW(0); }                                            \
    BARRIER();                                                                        \
  }

__global__ __launch_bounds__(512, 2) void gram_reduce_kernel(
    const u16* __restrict__ embB, const float* __restrict__ xx,
    const int* __restrict__ lab, unsigned* __restrict__ ap2, unsigned* __restrict__ an2)
{
    __shared__ u16 Ash[2 * BM * BK];   // 64 KiB, [buf][256 rows][64 cols], swizzled 16B slots
    __shared__ u16 Bsh[2 * BM * BK];   // 64 KiB
    __shared__ int labR[BM], labC[BM];
    __shared__ float xxR[BM], xxC[BM];

    const int tid = threadIdx.x;
    const int bid = blockIdx.x;
    const int swz = (bid & 7) * 32 + (bid >> 3);   // bijective: 256 % 8 == 0
    const int bm = swz >> 4, bn = swz & 15;
    const int row0 = bm * BM, col0 = bn * BM;

    // ---- staging constants: linear LDS dest (base + tid*16B), pre-swizzled global source
    const int csw = ((tid & 7) ^ ((tid >> 3) & 7)) * 8;      // involution: slot ^ (row&7)
    const u16* gA = embB + (size_t)(row0 + (tid >> 3)) * D_K + csw;
    const u16* gB = embB + (size_t)(col0 + (tid >> 3)) * D_K + csw;
    u16* lA = Ash + tid * 8;
    u16* lB = Bsh + tid * 8;
    const size_t g64 = (size_t)64 * D_K;

    // ---- fragment-read constants
    const int l = tid & 63, w = tid >> 6;
    const int wr = w >> 2, wc = w & 3;          // 2 x 4 wave grid, per-wave 128x64
    const int fr = l & 15, fkb = l >> 4;        // frag row / k-block
    const int frs = fr & 7;
    const int kx0 = (fkb ^ frs) * 16;           // swizzled k-offset bytes, ks=0
    const int kx1 = kx0 ^ 64;                   // ks=1
    const char* AB = (const char*)Ash;
    const char* BB = (const char*)Bsh;
    const int aOff = wr * 16384 + fr * 128;                           // + buf*32768 + m*2048
    const int bOff = (wc >> 1) * 16384 + ((wc & 1) * 64 + fr) * 128;  // + buf*32768 + n*2048

    f32x4 acc[8][4];
#pragma unroll
    for (int m = 0; m < 8; ++m)
#pragma unroll
        for (int n = 0; n < 4; ++n) acc[m][n] = (f32x4){0.f, 0.f, 0.f, 0.f};

    // ---- prologue: tile 0 fully staged into buf 0; publish A-c0,B-q01; 4 in flight
    STAGE_A(0, 0, 0, 0); STAGE_A(0, 1, 0, 0);
    STAGE_B(0, 0, 0); STAGE_B(0, 1, 0); STAGE_B(0, 2, 0); STAGE_B(0, 3, 0);
    STAGE_A(0, 0, 1, 0); STAGE_A(0, 1, 1, 0);
    VMW(4);
    BARRIER();

    // ---- main loop: 2 K-tiles per iteration, buf as compile-time constant
    for (int ii = 0; ii < NT / 2; ++ii) {
        const int kA = (2 * ii + 1) * BK;       // stage target: tile 2ii+1 -> buf 1
        const int kB = (2 * ii + 2) * BK;       // stage target: tile 2ii+2 -> buf 0
        const bool okB = (ii + 1 < NT / 2);
        KTILE(0, 1, kA, true)
        KTILE(1, 0, kB, okB)
    }

    // ---- epilogue metadata (only needed here)
    if (tid < 256) { labR[tid] = lab[row0 + tid]; xxR[tid] = xx[row0 + tid]; }
    else           { int u2 = tid - 256; labC[u2] = lab[col0 + u2]; xxC[u2] = xx[col0 + u2]; }
    __syncthreads();

    // ---- epilogue: d2 = xx_i + xx_j - 2g, clamp, masked max/min, 16-lane reduce, atomics
    const int rgrp = l >> 4;
#pragma unroll
    for (int m = 0; m < 8; ++m) {
#pragma unroll
        for (int r = 0; r < 4; ++r) {
            const int il = wr * 128 + m * 16 + rgrp * 4 + r;   // C/D row = (lane>>4)*4 + reg
            const int li = labR[il];
            const float xi = xxR[il];
            float apv = 0.f, anv = __FLT_MAX__;
#pragma unroll
            for (int n = 0; n < 4; ++n) {
                const int jl = wc * 64 + n * 16 + fr;          // C/D col = lane&15
                float d2 = xi + xxC[jl] - 2.f * acc[m][n][r];
                d2 = fmaxf(d2, 1e-12f);
                const bool same = (labC[jl] == li);
                apv = same ? fmaxf(apv, d2) : apv;
                anv = same ? anv : fminf(anv, d2);
            }
#pragma unroll
            for (int off = 1; off < 16; off <<= 1) {
                apv = fmaxf(apv, __shfl_xor(apv, off, 64));
                anv = fminf(anv, __shfl_xor(anv, off, 64));
            }
            if (fr == 0) {
                atomicMax(&ap2[row0 + il], __float_as_uint(apv));
                atomicMin(&an2[row0 + il], __float_as_uint(anv));
            }
        }
    }
}

// ---------- Kernel 3: finalize loss + precision ----------
__global__ __launch_bounds__(256) void finalize_kernel(
    const unsigned* __restrict__ ap2, const unsigned* __restrict__ an2, float* __restrict__ out)
{
    const int t = threadIdx.x;
    float ls = 0.f, ps = 0.f;
    for (int i = t; i < N_ROWS; i += 256) {
        const float ap = sqrtf(__uint_as_float(ap2[i]));
        const float an = sqrtf(__uint_as_float(an2[i]));
        ls += fmaxf(MARGIN - an + ap, 0.f);
        ps += (an > ap) ? 1.f : 0.f;
    }
#pragma unroll
    for (int off = 32; off >= 1; off >>= 1) {
        ls += __shfl_down(ls, off, 64);
        ps += __shfl_down(ps, off, 64);
    }
    __shared__ float rl[4], rp[4];
    if ((t & 63) == 0) { rl[t >> 6] = ls; rp[t >> 6] = ps; }
    __syncthreads();
    if (t == 0) {
        out[0] = (rl[0] + rl[1] + rl[2] + rl[3]) * (1.f / N_ROWS);
        out[1] = (rp[0] + rp[1] + rp[2] + rp[3]) * (1.f / N_ROWS);
    }
}

extern "C" void kernel_launch(void* const* d_in, const int* in_sizes, int n_in,
                              void* d_out, int out_size, void* d_ws, size_t ws_size,
                              hipStream_t stream)
{
    const float* emb = (const float*)d_in[0];
    const int* lab = (const int*)d_in[1];
    float* out = (float*)d_out;

    char* ws = (char*)d_ws;
    u16* embB   = (u16*)ws;                                           // 16 MB
    float* xx   = (float*)(ws + (size_t)N_ROWS * D_K * 2);
    unsigned* ap2 = (unsigned*)(ws + (size_t)N_ROWS * D_K * 2 + N_ROWS * 4);
    unsigned* an2 = (unsigned*)(ws + (size_t)N_ROWS * D_K * 2 + 2 * (size_t)N_ROWS * 4);

    prep_kernel<<<N_ROWS, 256, 0, stream>>>(emb, embB, xx, ap2, an2);
    dim3 grid((N_ROWS / BM) * (N_ROWS / BM));   // 16*16 = 256 blocks, 1 per CU
    gram_reduce_kernel<<<grid, 512, 0, stream>>>(embB, xx, lab, ap2, an2);
    finalize_kernel<<<1, 256, 0, stream>>>(ap2, an2, out);
}

// Round 11
// 74.951 us; speedup vs baseline: 2.3006x; 1.1608x over previous
//
#include <hip/hip_runtime.h>

#define N_ROWS 4096
#define D_K    2048
#define BP   128                      // panel size
#define NPAN (N_ROWS / BP)            // 32 panels
#define NTRI (NPAN * (NPAN + 1) / 2)  // 528 triangle tiles
#define BK   32
#define NT   (D_K / BK)               // 64 K-tiles
#define MARGIN 0.3f

typedef unsigned short u16;
typedef __attribute__((ext_vector_type(8))) short bf16x8;
typedef __attribute__((ext_vector_type(4))) float f32x4;

__device__ __forceinline__ void stage16(const u16* src, u16* dst) {
    __builtin_amdgcn_global_load_lds((const __attribute__((address_space(1))) unsigned int*)src,
                                     (__attribute__((address_space(3))) unsigned int*)dst, 16, 0, 0);
}

__device__ __forceinline__ u16 f2bf(float f) {
    unsigned u = __float_as_uint(f);
    u += 0x7fffu + ((u >> 16) & 1u);   // round-to-nearest-even
    return (u16)(u >> 16);
}

// ---------- Kernel 1: fp32 -> bf16 convert, exact fp32 row norms, init ap2/an2 ----------
__global__ __launch_bounds__(256) void prep_kernel(
    const float* __restrict__ emb, u16* __restrict__ embB,
    float* __restrict__ xx, unsigned* __restrict__ ap2, unsigned* __restrict__ an2)
{
    const int row = blockIdx.x;
    const int t = threadIdx.x;
    const float4* src = (const float4*)(emb + (size_t)row * D_K);
    ushort4* dst = (ushort4*)(embB + (size_t)row * D_K);
    float s = 0.f;
#pragma unroll
    for (int i = 0; i < 2; ++i) {
        float4 v = src[t + i * 256];
        s = fmaf(v.x, v.x, s);
        s = fmaf(v.y, v.y, s);
        s = fmaf(v.z, v.z, s);
        s = fmaf(v.w, v.w, s);
        ushort4 o;
        o.x = f2bf(v.x); o.y = f2bf(v.y); o.z = f2bf(v.z); o.w = f2bf(v.w);
        dst[t + i * 256] = o;
    }
#pragma unroll
    for (int off = 32; off >= 1; off >>= 1) s += __shfl_down(s, off, 64);
    __shared__ float red[4];
    if ((t & 63) == 0) red[t >> 6] = s;
    __syncthreads();
    if (t == 0) {
        xx[row] = red[0] + red[1] + red[2] + red[3];
        ap2[row] = 0u;            // float 0.0
        an2[row] = 0x7f7fffffu;   // FLT_MAX
    }
}

// ---------- Kernel 2: triangle 128x128 tiles, m97-style engine, dual-reduction epilogue ----------
#define LDv(p) (*(const bf16x8*)(p))

__global__ __launch_bounds__(256) void gram_tri_kernel(
    const u16* __restrict__ embB, const float* __restrict__ xx,
    const int* __restrict__ lab, unsigned* __restrict__ ap2, unsigned* __restrict__ an2)
{
    __shared__ u16 As[BP * BK];   // 8 KiB, [128 rows][32 cols], 16B-slot swizzled
    __shared__ u16 Bs[BP * BK];   // 8 KiB
    __shared__ int labR[BP], labC[BP];
    __shared__ float xxR[BP], xxC[BP];

    const int tid = threadIdx.x;

    // XCD-aware bijective swizzle (528 = 66 * 8), then triangle unrank (I <= J)
    const int bid = blockIdx.x;
    const int p = (bid & 7) * (NTRI / 8) + (bid >> 3);
    int I = 0, rem = p;
    while (rem >= NPAN - I) { rem -= NPAN - I; ++I; }
    const int J = I + rem;
    const int row0 = I * BP, col0 = J * BP;
    const bool diag = (I == J);

    // ---- staging: linear LDS dest (tid*16B), pre-swizzled global source.
    // Row = 64B = 4 slots; involution: slot ^= (row>>1)&3  (r7-verified, 0 conflicts)
    const int csw = ((tid & 3) ^ ((tid >> 3) & 3)) * 8;   // u16 elements
    const int srow = tid >> 2;                            // 0..63
    const u16* gA0 = embB + (size_t)(row0 + srow) * D_K + csw;
    const u16* gA1 = embB + (size_t)(row0 + 64 + srow) * D_K + csw;
    const u16* gB0 = embB + (size_t)(col0 + srow) * D_K + csw;
    const u16* gB1 = embB + (size_t)(col0 + 64 + srow) * D_K + csw;
    u16* lA = As + tid * 8;
    u16* lB = Bs + tid * 8;

    // ---- fragment constants: 2x2 waves, wave (wr,wc) owns rows wr*64+.., cols wc*64+..
    const int l = tid & 63, w = tid >> 6;
    const int wr = w >> 1, wc = w & 1;
    const int fr = l & 15, fkb = l >> 4;            // frag row / k-slot
    const int kx = (fkb ^ ((fr >> 1) & 3)) * 16;    // swizzled 16B slot within 64B row (bytes)
    const char* AB = (const char*)As;
    const char* BB = (const char*)Bs;
    const int aOff = wr * 4096 + fr * 64;           // + m*1024 (bytes)
    const int bOff = wc * 4096 + fr * 64;           // + n*1024 (bytes)

    f32x4 acc[4][4];
#pragma unroll
    for (int m = 0; m < 4; ++m)
#pragma unroll
        for (int n = 0; n < 4; ++n) acc[m][n] = (f32x4){0.f, 0.f, 0.f, 0.f};

    // ---- m97-style K-loop: stage -> sync (drains vmcnt) -> read frags + 16 MFMA -> sync
    for (int kt = 0; kt < NT; ++kt) {
        const int ko = kt * BK;
        stage16(gA0 + ko, lA); stage16(gA1 + ko, lA + 2048);
        stage16(gB0 + ko, lB); stage16(gB1 + ko, lB + 2048);
        __syncthreads();
        bf16x8 aq[4], bq[4];
#pragma unroll
        for (int m = 0; m < 4; ++m) aq[m] = LDv(AB + aOff + m * 1024 + kx);
#pragma unroll
        for (int n = 0; n < 4; ++n) bq[n] = LDv(BB + bOff + n * 1024 + kx);
#pragma unroll
        for (int m = 0; m < 4; ++m)
#pragma unroll
            for (int n = 0; n < 4; ++n)
                acc[m][n] = __builtin_amdgcn_mfma_f32_16x16x32_bf16(aq[m], bq[n], acc[m][n], 0, 0, 0);
        __syncthreads();
    }

    // ---- epilogue metadata
    if (tid < BP)      { labR[tid] = lab[row0 + tid]; xxR[tid] = xx[row0 + tid]; }
    else               { int u2 = tid - BP; labC[u2] = lab[col0 + u2]; xxC[u2] = xx[col0 + u2]; }
    __syncthreads();

    const int rgrp = l >> 4;

    // ---- ROW pass: output rows = panel I; reduce over this tile's 128 cols
    // C/D: row = m*16 + rgrp*4 + r (+wr*64), col = n*16 + fr (+wc*64)
#pragma unroll
    for (int m = 0; m < 4; ++m) {
#pragma unroll
        for (int r = 0; r < 4; ++r) {
            const int il = wr * 64 + m * 16 + rgrp * 4 + r;
            const int li = labR[il];
            const float xi = xxR[il];
            float apv = 0.f, anv = __FLT_MAX__;
#pragma unroll
            for (int n = 0; n < 4; ++n) {
                const int jl = wc * 64 + n * 16 + fr;
                float d2 = xi + xxC[jl] - 2.f * acc[m][n][r];
                d2 = fmaxf(d2, 1e-12f);
                const bool same = (labC[jl] == li);
                apv = same ? fmaxf(apv, d2) : apv;
                anv = same ? anv : fminf(anv, d2);
            }
#pragma unroll
            for (int off = 1; off < 16; off <<= 1) {   // fold 16 fr-lanes (in-group)
                apv = fmaxf(apv, __shfl_xor(apv, off, 64));
                anv = fminf(anv, __shfl_xor(anv, off, 64));
            }
            if (fr == 0) {
                atomicMax(&ap2[row0 + il], __float_as_uint(apv));
                atomicMin(&an2[row0 + il], __float_as_uint(anv));
            }
        }
    }

    // ---- COL pass (off-diagonal tiles only): output rows = panel J; reduce over tile's 128 rows
    if (!diag) {
#pragma unroll
        for (int n = 0; n < 4; ++n) {
            const int jl = wc * 64 + n * 16 + fr;
            const int lj = labC[jl];
            const float xj = xxC[jl];
            float apv = 0.f, anv = __FLT_MAX__;
#pragma unroll
            for (int m = 0; m < 4; ++m) {
#pragma unroll
                for (int r = 0; r < 4; ++r) {
                    const int il = wr * 64 + m * 16 + rgrp * 4 + r;
                    float d2 = xj + xxR[il] - 2.f * acc[m][n][r];
                    d2 = fmaxf(d2, 1e-12f);
                    const bool same = (labR[il] == lj);
                    apv = same ? fmaxf(apv, d2) : apv;
                    anv = same ? anv : fminf(anv, d2);
                }
            }
            // fold rgrp groups (lanes differ in bits 4-5; fr/col preserved)
            apv = fmaxf(apv, __shfl_xor(apv, 16, 64));
            anv = fminf(anv, __shfl_xor(anv, 16, 64));
            apv = fmaxf(apv, __shfl_xor(apv, 32, 64));
            anv = fminf(anv, __shfl_xor(anv, 32, 64));
            if (rgrp == 0) {   // one lane per col per wave; both wr waves merge via atomics
                atomicMax(&ap2[col0 + jl], __float_as_uint(apv));
                atomicMin(&an2[col0 + jl], __float_as_uint(anv));
            }
        }
    }
}

// ---------- Kernel 3: finalize loss + precision ----------
__global__ __launch_bounds__(256) void finalize_kernel(
    const unsigned* __restrict__ ap2, const unsigned* __restrict__ an2, float* __restrict__ out)
{
    const int t = threadIdx.x;
    float ls = 0.f, ps = 0.f;
    for (int i = t; i < N_ROWS; i += 256) {
        const float ap = sqrtf(__uint_as_float(ap2[i]));
        const float an = sqrtf(__uint_as_float(an2[i]));
        ls += fmaxf(MARGIN - an + ap, 0.f);
        ps += (an > ap) ? 1.f : 0.f;
    }
#pragma unroll
    for (int off = 32; off >= 1; off >>= 1) {
        ls += __shfl_down(ls, off, 64);
        ps += __shfl_down(ps, off, 64);
    }
    __shared__ float rl[4], rp[4];
    if ((t & 63) == 0) { rl[t >> 6] = ls; rp[t >> 6] = ps; }
    __syncthreads();
    if (t == 0) {
        out[0] = (rl[0] + rl[1] + rl[2] + rl[3]) * (1.f / N_ROWS);
        out[1] = (rp[0] + rp[1] + rp[2] + rp[3]) * (1.f / N_ROWS);
    }
}

extern "C" void kernel_launch(void* const* d_in, const int* in_sizes, int n_in,
                              void* d_out, int out_size, void* d_ws, size_t ws_size,
                              hipStream_t stream)
{
    const float* emb = (const float*)d_in[0];
    const int* lab = (const int*)d_in[1];
    float* out = (float*)d_out;

    char* ws = (char*)d_ws;
    u16* embB   = (u16*)ws;                                           // 16 MB
    float* xx   = (float*)(ws + (size_t)N_ROWS * D_K * 2);
    unsigned* ap2 = (unsigned*)(ws + (size_t)N_ROWS * D_K * 2 + N_ROWS * 4);
    unsigned* an2 = (unsigned*)(ws + (size_t)N_ROWS * D_K * 2 + 2 * (size_t)N_ROWS * 4);

    prep_kernel<<<N_ROWS, 256, 0, stream>>>(emb, embB, xx, ap2, an2);
    gram_tri_kernel<<<NTRI, 256, 0, stream>>>(embB, xx, lab, ap2, an2);   // 528 blocks
    finalize_kernel<<<1, 256, 0, stream>>>(ap2, an2, out);
}